// Round 1
// baseline (970.722 us; speedup 1.0000x reference)
//
#include <hip/hip_runtime.h>
#include <hip/hip_bf16.h>
#include <stdint.h>

typedef __attribute__((ext_vector_type(8))) short bf16x8;
typedef __attribute__((ext_vector_type(4))) float f32x4;

#define BM 128
#define BN 128
#define BK 64

struct Scalars {
  double sum_wk;          // sum |Wk|
  double sum_wo;          // sum |Wo|
  unsigned int max_x_bits;  // max|x| as uint bits (nonneg float)
  unsigned int max_y_bits;  // max|x+retrieved| as uint bits
};

__device__ __forceinline__ unsigned short f2bf(float f) {
  __hip_bfloat16 h = __float2bfloat16(f);
  return *reinterpret_cast<unsigned short*>(&h);
}

// async global->LDS, 16B per lane; LDS dest must be wave-uniform base (HW: base + lane*16)
__device__ __forceinline__ void async16(void* lds, const void* g) {
  __builtin_amdgcn_global_load_lds((__attribute__((address_space(1))) void*)g,
                                   (__attribute__((address_space(3))) void*)lds, 16, 0, 0);
}

// ---------------- reductions ----------------
__global__ __launch_bounds__(256) void abssum_kernel(const float* __restrict__ w, size_t n,
                                                     double* __restrict__ out) {
  size_t tid = (size_t)blockIdx.x * blockDim.x + threadIdx.x;
  size_t stride = (size_t)gridDim.x * blockDim.x;
  double s = 0.0;
  for (size_t i = tid * 4; i < n; i += stride * 4) {
    float4 v = *(const float4*)(w + i);
    s += (double)fabsf(v.x) + (double)fabsf(v.y) + (double)fabsf(v.z) + (double)fabsf(v.w);
  }
#pragma unroll
  for (int o = 32; o > 0; o >>= 1) s += __shfl_xor(s, o);
  __shared__ double sm[4];
  if ((threadIdx.x & 63) == 0) sm[threadIdx.x >> 6] = s;
  __syncthreads();
  if (threadIdx.x == 0) atomicAdd(out, sm[0] + sm[1] + sm[2] + sm[3]);
}

__global__ __launch_bounds__(256) void absmax_kernel(const float* __restrict__ x, size_t n,
                                                     unsigned int* __restrict__ out) {
  size_t tid = (size_t)blockIdx.x * blockDim.x + threadIdx.x;
  size_t stride = (size_t)gridDim.x * blockDim.x;
  float m = 0.0f;
  for (size_t i = tid * 4; i < n; i += stride * 4) {
    float4 v = *(const float4*)(x + i);
    m = fmaxf(m, fmaxf(fmaxf(fabsf(v.x), fabsf(v.y)), fmaxf(fabsf(v.z), fabsf(v.w))));
  }
#pragma unroll
  for (int o = 32; o > 0; o >>= 1) m = fmaxf(m, __shfl_xor(m, o));
  __shared__ float sm[4];
  if ((threadIdx.x & 63) == 0) sm[threadIdx.x >> 6] = m;
  __syncthreads();
  if (threadIdx.x == 0)
    atomicMax(out, __float_as_uint(fmaxf(fmaxf(sm[0], sm[1]), fmaxf(sm[2], sm[3]))));
}

// ---------------- quantize / cast ----------------
__global__ __launch_bounds__(256) void quant_act_kernel(const float* __restrict__ x,
                                                        __hip_bfloat16* __restrict__ q,
                                                        const unsigned int* __restrict__ maxbits,
                                                        size_t n) {
  const float isc = __uint_as_float(*maxbits) / 127.0f;  // matches np: max/127.0 in fp32
  size_t tid = (size_t)blockIdx.x * blockDim.x + threadIdx.x;
  size_t stride = (size_t)gridDim.x * blockDim.x;
  for (size_t i = tid * 4; i < n; i += stride * 4) {
    float4 v = *(const float4*)(x + i);
    ushort4 o;
    o.x = f2bf(fminf(fmaxf(rintf(v.x / isc), -128.f), 127.f));
    o.y = f2bf(fminf(fmaxf(rintf(v.y / isc), -128.f), 127.f));
    o.z = f2bf(fminf(fmaxf(rintf(v.z / isc), -128.f), 127.f));
    o.w = f2bf(fminf(fmaxf(rintf(v.w / isc), -128.f), 127.f));
    *(ushort4*)((unsigned short*)q + i) = o;
  }
}

__global__ __launch_bounds__(256) void quant_w_kernel(const float* __restrict__ W,
                                                      __hip_bfloat16* __restrict__ qW,
                                                      const double* __restrict__ sum, size_t n) {
  const float wsc = (float)(*sum / (double)n);
  const float thr = 0.5f * wsc;
  size_t tid = (size_t)blockIdx.x * blockDim.x + threadIdx.x;
  size_t stride = (size_t)gridDim.x * blockDim.x;
  for (size_t i = tid * 4; i < n; i += stride * 4) {
    float4 v = *(const float4*)(W + i);
    ushort4 o;
    o.x = f2bf(fabsf(v.x) > thr ? (v.x > 0.f ? 1.f : -1.f) : 0.f);
    o.y = f2bf(fabsf(v.y) > thr ? (v.y > 0.f ? 1.f : -1.f) : 0.f);
    o.z = f2bf(fabsf(v.z) > thr ? (v.z > 0.f ? 1.f : -1.f) : 0.f);
    o.w = f2bf(fabsf(v.w) > thr ? (v.w > 0.f ? 1.f : -1.f) : 0.f);
    *(ushort4*)((unsigned short*)qW + i) = o;
  }
}

__global__ __launch_bounds__(256) void cast_bf16_kernel(const float* __restrict__ src,
                                                        __hip_bfloat16* __restrict__ dst,
                                                        size_t n) {
  size_t tid = (size_t)blockIdx.x * blockDim.x + threadIdx.x;
  size_t stride = (size_t)gridDim.x * blockDim.x;
  for (size_t i = tid * 4; i < n; i += stride * 4) {
    float4 v = *(const float4*)(src + i);
    ushort4 o;
    o.x = f2bf(v.x); o.y = f2bf(v.y); o.z = f2bf(v.z); o.w = f2bf(v.w);
    *(ushort4*)((unsigned short*)dst + i) = o;
  }
}

// memory_values [2048][1024] f32 -> mvT [1024][2048] bf16
__global__ void transpose_mv_kernel(const float* __restrict__ mv,
                                    __hip_bfloat16* __restrict__ mvT) {
  __shared__ float tile[32][33];
  int tx = threadIdx.x, ty = threadIdx.y;
  int e = blockIdx.x * 32 + tx;
  int m = blockIdx.y * 32 + ty;
  tile[ty][tx] = mv[(size_t)m * 1024 + e];
  __syncthreads();
  int oe = blockIdx.x * 32 + ty;
  int om = blockIdx.y * 32 + tx;
  mvT[(size_t)oe * 2048 + om] = __float2bfloat16(tile[tx][ty]);
}

// ---------------- softmax over rows of 2048, in-place bf16 ----------------
__global__ __launch_bounds__(256) void softmax_kernel(__hip_bfloat16* __restrict__ sims) {
  unsigned short* row = (unsigned short*)(sims + (size_t)blockIdx.x * 2048);
  const int t = threadIdx.x;
  const int l = t & 63, wv = t >> 6;
  uint4 r4 = *(const uint4*)(row + t * 8);
  float v[8];
  v[0] = __uint_as_float(r4.x << 16); v[1] = __uint_as_float(r4.x & 0xffff0000u);
  v[2] = __uint_as_float(r4.y << 16); v[3] = __uint_as_float(r4.y & 0xffff0000u);
  v[4] = __uint_as_float(r4.z << 16); v[5] = __uint_as_float(r4.z & 0xffff0000u);
  v[6] = __uint_as_float(r4.w << 16); v[7] = __uint_as_float(r4.w & 0xffff0000u);
  float m = v[0];
#pragma unroll
  for (int i = 1; i < 8; ++i) m = fmaxf(m, v[i]);
#pragma unroll
  for (int o = 32; o > 0; o >>= 1) m = fmaxf(m, __shfl_xor(m, o));
  __shared__ float red[4], red2[4];
  if (l == 0) red[wv] = m;
  __syncthreads();
  m = fmaxf(fmaxf(red[0], red[1]), fmaxf(red[2], red[3]));
  float s = 0.f;
#pragma unroll
  for (int i = 0; i < 8; ++i) { v[i] = expf(v[i] - m); s += v[i]; }
#pragma unroll
  for (int o = 32; o > 0; o >>= 1) s += __shfl_xor(s, o);
  if (l == 0) red2[wv] = s;
  __syncthreads();
  s = red2[0] + red2[1] + red2[2] + red2[3];
  unsigned short b[8];
#pragma unroll
  for (int i = 0; i < 8; ++i) b[i] = f2bf(v[i] / s);
  uint4 o4;
  o4.x = (unsigned)b[0] | ((unsigned)b[1] << 16);
  o4.y = (unsigned)b[2] | ((unsigned)b[3] << 16);
  o4.z = (unsigned)b[4] | ((unsigned)b[5] << 16);
  o4.w = (unsigned)b[6] | ((unsigned)b[7] << 16);
  *(uint4*)(row + t * 8) = o4;
}

// ---------------- 128x128 NT bf16 MFMA GEMM, C[m,n] = sum_k A[m,k]*B[n,k] ----------------
// EPI 0: C=bf16( acc*s_k + bias[col] )   (s_k = w_scale_k * i_scale_x, from Scalars)
// EPI 1: C=bf16( acc * (1/32) )
// EPI 2: C=f32 ( acc + Xadd )  + global absmax -> sc->max_y_bits
// EPI 3: C=f32 ( acc*s_o + bias[col] )   (s_o = w_scale_o * i_scale_y)
template <int EPI>
__global__ __launch_bounds__(256) void gemm_bt(
    const __hip_bfloat16* __restrict__ A, const __hip_bfloat16* __restrict__ B,
    void* __restrict__ C, const float* __restrict__ bias, const float* __restrict__ Xadd,
    Scalars* __restrict__ sc, int Mdim, int Ndim, int Kdim) {
  __shared__ __hip_bfloat16 sA[BM * BK];
  __shared__ __hip_bfloat16 sB[BN * BK];
  __shared__ float wred[4];

  const int t = threadIdx.x;
  const int w = t >> 6;       // wave 0..3, 2x2 over the 128x128 tile
  const int l = t & 63;
  const int wm = w >> 1, wn = w & 1;
  const int quad = l >> 4;
  const int m16 = l & 15;

  const int rowBlk = blockIdx.y * BM;
  const int colBlk = blockIdx.x * BN;

  // staging: each 1KB chunk = 8 rows x 64 bf16; lane covers 16B.
  // XOR swizzle of 16B sub-chunks within a row (pos p holds data chunk p ^ (row%8))
  const int rIn = l >> 3;
  const int dIn = (l & 7) ^ rIn;

  f32x4 acc[4][4] = {};

  for (int kb = 0; kb < Kdim; kb += BK) {
#pragma unroll
    for (int i = 0; i < 4; ++i) {
      const int c = w + 4 * i;           // chunk 0..15
      const int r = 8 * c + rIn;         // tile row
      const __hip_bfloat16* ga = A + (size_t)(rowBlk + r) * Kdim + kb + dIn * 8;
      const __hip_bfloat16* gb = B + (size_t)(colBlk + r) * Kdim + kb + dIn * 8;
      async16(&sA[c * 512], ga);
      async16(&sB[c * 512], gb);
    }
    __syncthreads();

#pragma unroll
    for (int ks = 0; ks < 2; ++ks) {
      bf16x8 af[4], bfr[4];
#pragma unroll
      for (int i = 0; i < 4; ++i) {
        const int r = wm * 64 + i * 16 + m16;
        const int p = (ks * 4 + quad) ^ (r & 7);
        af[i] = *(const bf16x8*)(&sA[r * 64 + p * 8]);
      }
#pragma unroll
      for (int j = 0; j < 4; ++j) {
        const int r = wn * 64 + j * 16 + m16;
        const int p = (ks * 4 + quad) ^ (r & 7);
        bfr[j] = *(const bf16x8*)(&sB[r * 64 + p * 8]);
      }
#pragma unroll
      for (int i = 0; i < 4; ++i)
#pragma unroll
        for (int j = 0; j < 4; ++j)
          acc[i][j] = __builtin_amdgcn_mfma_f32_16x16x32_bf16(af[i], bfr[j], acc[i][j], 0, 0, 0);
    }
    __syncthreads();
  }

  float s = 1.0f;
  if (EPI == 0) {
    float wsc = (float)(sc->sum_wk * (1.0 / 1048576.0));
    float isc = __uint_as_float(sc->max_x_bits) / 127.0f;
    s = wsc * isc;
  } else if (EPI == 1) {
    s = 0.03125f;
  } else if (EPI == 3) {
    float wsc = (float)(sc->sum_wo * (1.0 / 1048576.0));
    float isc = __uint_as_float(sc->max_y_bits) / 127.0f;
    s = wsc * isc;
  }

  float amax = 0.0f;
#pragma unroll
  for (int i = 0; i < 4; ++i) {
#pragma unroll
    for (int j = 0; j < 4; ++j) {
      const int col = colBlk + wn * 64 + j * 16 + m16;
#pragma unroll
      for (int rg = 0; rg < 4; ++rg) {
        const int row = rowBlk + wm * 64 + i * 16 + quad * 4 + rg;
        float v = acc[i][j][rg];
        if (EPI == 0) {
          v = v * s + bias[col];
          ((__hip_bfloat16*)C)[(size_t)row * Ndim + col] = __float2bfloat16(v);
        } else if (EPI == 1) {
          ((__hip_bfloat16*)C)[(size_t)row * Ndim + col] = __float2bfloat16(v * s);
        } else if (EPI == 2) {
          v += Xadd[(size_t)row * Ndim + col];
          ((float*)C)[(size_t)row * Ndim + col] = v;
          amax = fmaxf(amax, fabsf(v));
        } else {
          ((float*)C)[(size_t)row * Ndim + col] = v * s + bias[col];
        }
      }
    }
  }

  if (EPI == 2) {
#pragma unroll
    for (int o = 32; o > 0; o >>= 1) amax = fmaxf(amax, __shfl_xor(amax, o));
    if (l == 0) wred[w] = amax;
    __syncthreads();
    if (t == 0)
      atomicMax(&sc->max_y_bits,
                __float_as_uint(fmaxf(fmaxf(wred[0], wred[1]), fmaxf(wred[2], wred[3]))));
  }
}

extern "C" void kernel_launch(void* const* d_in, const int* in_sizes, int n_in,
                              void* d_out, int out_size, void* d_ws, size_t ws_size,
                              hipStream_t stream) {
  (void)in_sizes; (void)n_in; (void)out_size; (void)ws_size;
  const float* x  = (const float*)d_in[0];   // [8,4096,1024]
  const float* mk = (const float*)d_in[1];   // [2048,1024]
  const float* mv = (const float*)d_in[2];   // [2048,1024]
  const float* Wk = (const float*)d_in[3];   // [1024,1024]
  const float* bk = (const float*)d_in[4];   // [1024]
  // d_in[5], d_in[6] = Wv, bv -> _query_values is dead code w.r.t. output; skipped.
  const float* Wo = (const float*)d_in[7];
  const float* bo = (const float*)d_in[8];
  float* out = (float*)d_out;

  const int M = 32768, E = 1024, MEM = 2048;

  char* ws = (char*)d_ws;
  Scalars* sc = (Scalars*)ws;
  const size_t off0 = 256;
  __hip_bfloat16* qx = (__hip_bfloat16*)(ws + off0);                       // 64 MB
  __hip_bfloat16* qk = (__hip_bfloat16*)(ws + off0 + (size_t)M * E * 2);   // 64 MB
  float* y = (float*)(ws + off0);                                          // reuses qx+qk (128 MB)
  const size_t off1 = off0 + (size_t)M * E * 4;
  __hip_bfloat16* sims = (__hip_bfloat16*)(ws + off1);                     // 128 MB
  __hip_bfloat16* qy = sims;                                               // reuses sims
  const size_t off2 = off1 + (size_t)M * MEM * 2;
  __hip_bfloat16* qWk = (__hip_bfloat16*)(ws + off2);                      // 2 MB
  __hip_bfloat16* qWo = qWk + (size_t)E * E;                               // 2 MB
  __hip_bfloat16* mkb = qWo + (size_t)E * E;                               // 4 MB
  __hip_bfloat16* mvT = mkb + (size_t)MEM * E;                             // 4 MB

  hipMemsetAsync(ws, 0, 256, stream);

  abssum_kernel<<<dim3(256), dim3(256), 0, stream>>>(Wk, (size_t)E * E, &sc->sum_wk);
  abssum_kernel<<<dim3(256), dim3(256), 0, stream>>>(Wo, (size_t)E * E, &sc->sum_wo);
  absmax_kernel<<<dim3(2048), dim3(256), 0, stream>>>(x, (size_t)M * E, &sc->max_x_bits);

  quant_act_kernel<<<dim3(2048), dim3(256), 0, stream>>>(x, qx, &sc->max_x_bits, (size_t)M * E);
  quant_w_kernel<<<dim3(256), dim3(256), 0, stream>>>(Wk, qWk, &sc->sum_wk, (size_t)E * E);
  quant_w_kernel<<<dim3(256), dim3(256), 0, stream>>>(Wo, qWo, &sc->sum_wo, (size_t)E * E);
  cast_bf16_kernel<<<dim3(256), dim3(256), 0, stream>>>(mk, mkb, (size_t)MEM * E);
  transpose_mv_kernel<<<dim3(E / 32, MEM / 32), dim3(32, 32), 0, stream>>>(mv, mvT);

  // qk = bf16((qx @ qWk^T) * s_k + bk)
  gemm_bt<0><<<dim3(E / BN, M / BM), dim3(256), 0, stream>>>(qx, qWk, qk, bk, nullptr, sc, M, E, E);
  // sims = bf16((qk @ mk^T) / 32)
  gemm_bt<1><<<dim3(MEM / BN, M / BM), dim3(256), 0, stream>>>(qk, mkb, sims, nullptr, nullptr, sc, M, MEM, E);
  // softmax rows (in place)
  softmax_kernel<<<dim3(M), dim3(256), 0, stream>>>(sims);
  // y = probs @ mv + x   (+ global max|y|)
  gemm_bt<2><<<dim3(E / BN, M / BM), dim3(256), 0, stream>>>(sims, mvT, y, nullptr, x, sc, M, E, MEM);
  // qy = quant(y)
  quant_act_kernel<<<dim3(2048), dim3(256), 0, stream>>>(y, qy, &sc->max_y_bits, (size_t)M * E);
  // out = (qy @ qWo^T) * s_o + bo
  gemm_bt<3><<<dim3(E / BN, M / BM), dim3(256), 0, stream>>>(qy, qWo, out, bo, nullptr, sc, M, E, E);
}

// Round 2
// 850.160 us; speedup vs baseline: 1.1418x; 1.1418x over previous
//
#include <hip/hip_runtime.h>
#include <hip/hip_bf16.h>
#include <stdint.h>

typedef __attribute__((ext_vector_type(8))) short bf16x8;
typedef __attribute__((ext_vector_type(4))) float f32x4;
typedef __attribute__((ext_vector_type(4))) int i32x4;

#define BM 128
#define BN 128
#define BK 64

struct Scalars {
  double sum_wk;            // sum |Wk|
  double sum_wo;            // sum |Wo|
  unsigned int max_x_bits;  // max|x| as uint bits (nonneg float)
  unsigned int max_y_bits;  // max|x+retrieved| as uint bits
};

__device__ __forceinline__ unsigned short f2bf(float f) {
  __hip_bfloat16 h = __float2bfloat16(f);
  return *reinterpret_cast<unsigned short*>(&h);
}

// async global->LDS, 16B per lane; LDS dest is wave-uniform base + lane*16
__device__ __forceinline__ void async16(void* lds, const void* g) {
  __builtin_amdgcn_global_load_lds((__attribute__((address_space(1))) void*)g,
                                   (__attribute__((address_space(3))) void*)lds, 16, 0, 0);
}

// XCD-aware tile swizzle: consecutive blockIdx go round-robin to XCDs (bid%8);
// give each XCD a contiguous run of row-strips, col-blocks innermost, so each
// A row-strip is fetched into exactly one XCD's L2.
__device__ __forceinline__ void tile_swizzle(int nxShift, int& bx, int& by) {
  const int per = gridDim.x >> 3;
  const int tile = (blockIdx.x & 7) * per + (blockIdx.x >> 3);
  bx = tile & ((1 << nxShift) - 1);
  by = tile >> nxShift;
}

// ---------------- reductions ----------------
__global__ __launch_bounds__(256) void abssum_kernel(const float* __restrict__ w, size_t n,
                                                     double* __restrict__ out) {
  size_t tid = (size_t)blockIdx.x * blockDim.x + threadIdx.x;
  size_t stride = (size_t)gridDim.x * blockDim.x;
  double s = 0.0;
  for (size_t i = tid * 4; i < n; i += stride * 4) {
    float4 v = *(const float4*)(w + i);
    s += (double)fabsf(v.x) + (double)fabsf(v.y) + (double)fabsf(v.z) + (double)fabsf(v.w);
  }
#pragma unroll
  for (int o = 32; o > 0; o >>= 1) s += __shfl_xor(s, o);
  __shared__ double sm[4];
  if ((threadIdx.x & 63) == 0) sm[threadIdx.x >> 6] = s;
  __syncthreads();
  if (threadIdx.x == 0) atomicAdd(out, sm[0] + sm[1] + sm[2] + sm[3]);
}

__global__ __launch_bounds__(256) void absmax_kernel(const float* __restrict__ x, size_t n,
                                                     unsigned int* __restrict__ out) {
  size_t tid = (size_t)blockIdx.x * blockDim.x + threadIdx.x;
  size_t stride = (size_t)gridDim.x * blockDim.x;
  float m = 0.0f;
  for (size_t i = tid * 4; i < n; i += stride * 4) {
    float4 v = *(const float4*)(x + i);
    m = fmaxf(m, fmaxf(fmaxf(fabsf(v.x), fabsf(v.y)), fmaxf(fabsf(v.z), fabsf(v.w))));
  }
#pragma unroll
  for (int o = 32; o > 0; o >>= 1) m = fmaxf(m, __shfl_xor(m, o));
  __shared__ float sm[4];
  if ((threadIdx.x & 63) == 0) sm[threadIdx.x >> 6] = m;
  __syncthreads();
  if (threadIdx.x == 0)
    atomicMax(out, __float_as_uint(fmaxf(fmaxf(sm[0], sm[1]), fmaxf(sm[2], sm[3]))));
}

// ---------------- quantize / cast (int8 paths) ----------------
__global__ __launch_bounds__(256) void quant_act_i8_kernel(const float* __restrict__ x,
                                                           char* __restrict__ q,
                                                           const unsigned int* __restrict__ maxbits,
                                                           size_t n) {
  const float isc = __uint_as_float(*maxbits) / 127.0f;  // matches np: max/127.0 fp32
  size_t tid = (size_t)blockIdx.x * blockDim.x + threadIdx.x;
  size_t stride = (size_t)gridDim.x * blockDim.x;
  for (size_t i = tid * 4; i < n; i += stride * 4) {
    float4 v = *(const float4*)(x + i);
    char4 o;
    o.x = (char)(int)fminf(fmaxf(rintf(v.x / isc), -128.f), 127.f);
    o.y = (char)(int)fminf(fmaxf(rintf(v.y / isc), -128.f), 127.f);
    o.z = (char)(int)fminf(fmaxf(rintf(v.z / isc), -128.f), 127.f);
    o.w = (char)(int)fminf(fmaxf(rintf(v.w / isc), -128.f), 127.f);
    *(char4*)(q + i) = o;
  }
}

__global__ __launch_bounds__(256) void quant_w_i8_kernel(const float* __restrict__ W,
                                                         char* __restrict__ qW,
                                                         const double* __restrict__ sum, size_t n) {
  const float wsc = (float)(*sum / (double)n);
  const float thr = 0.5f * wsc;
  size_t tid = (size_t)blockIdx.x * blockDim.x + threadIdx.x;
  size_t stride = (size_t)gridDim.x * blockDim.x;
  for (size_t i = tid * 4; i < n; i += stride * 4) {
    float4 v = *(const float4*)(W + i);
    char4 o;
    o.x = (char)(fabsf(v.x) > thr ? (v.x > 0.f ? 1 : -1) : 0);
    o.y = (char)(fabsf(v.y) > thr ? (v.y > 0.f ? 1 : -1) : 0);
    o.z = (char)(fabsf(v.z) > thr ? (v.z > 0.f ? 1 : -1) : 0);
    o.w = (char)(fabsf(v.w) > thr ? (v.w > 0.f ? 1 : -1) : 0);
    *(char4*)(qW + i) = o;
  }
}

__global__ __launch_bounds__(256) void cast_bf16_kernel(const float* __restrict__ src,
                                                        __hip_bfloat16* __restrict__ dst,
                                                        size_t n) {
  size_t tid = (size_t)blockIdx.x * blockDim.x + threadIdx.x;
  size_t stride = (size_t)gridDim.x * blockDim.x;
  for (size_t i = tid * 4; i < n; i += stride * 4) {
    float4 v = *(const float4*)(src + i);
    ushort4 o;
    o.x = f2bf(v.x); o.y = f2bf(v.y); o.z = f2bf(v.z); o.w = f2bf(v.w);
    *(ushort4*)((unsigned short*)dst + i) = o;
  }
}

// memory_values [2048][1024] f32 -> mvT [1024][2048] bf16
__global__ void transpose_mv_kernel(const float* __restrict__ mv,
                                    __hip_bfloat16* __restrict__ mvT) {
  __shared__ float tile[32][33];
  int tx = threadIdx.x, ty = threadIdx.y;
  int e = blockIdx.x * 32 + tx;
  int m = blockIdx.y * 32 + ty;
  tile[ty][tx] = mv[(size_t)m * 1024 + e];
  __syncthreads();
  int om = blockIdx.y * 32 + tx;
  mvT[(size_t)(blockIdx.x * 32 + ty) * 2048 + om] = __float2bfloat16(tile[tx][ty]);
}

// ---------------- softmax over rows of 2048, in-place bf16 ----------------
__global__ __launch_bounds__(256) void softmax_kernel(__hip_bfloat16* __restrict__ sims) {
  unsigned short* row = (unsigned short*)(sims + (size_t)blockIdx.x * 2048);
  const int t = threadIdx.x;
  const int l = t & 63, wv = t >> 6;
  uint4 r4 = *(const uint4*)(row + t * 8);
  float v[8];
  v[0] = __uint_as_float(r4.x << 16); v[1] = __uint_as_float(r4.x & 0xffff0000u);
  v[2] = __uint_as_float(r4.y << 16); v[3] = __uint_as_float(r4.y & 0xffff0000u);
  v[4] = __uint_as_float(r4.z << 16); v[5] = __uint_as_float(r4.z & 0xffff0000u);
  v[6] = __uint_as_float(r4.w << 16); v[7] = __uint_as_float(r4.w & 0xffff0000u);
  float m = v[0];
#pragma unroll
  for (int i = 1; i < 8; ++i) m = fmaxf(m, v[i]);
#pragma unroll
  for (int o = 32; o > 0; o >>= 1) m = fmaxf(m, __shfl_xor(m, o));
  __shared__ float red[4], red2[4];
  if (l == 0) red[wv] = m;
  __syncthreads();
  m = fmaxf(fmaxf(red[0], red[1]), fmaxf(red[2], red[3]));
  float s = 0.f;
#pragma unroll
  for (int i = 0; i < 8; ++i) { v[i] = expf(v[i] - m); s += v[i]; }
#pragma unroll
  for (int o = 32; o > 0; o >>= 1) s += __shfl_xor(s, o);
  if (l == 0) red2[wv] = s;
  __syncthreads();
  s = red2[0] + red2[1] + red2[2] + red2[3];
  unsigned short b[8];
#pragma unroll
  for (int i = 0; i < 8; ++i) b[i] = f2bf(v[i] / s);
  uint4 o4;
  o4.x = (unsigned)b[0] | ((unsigned)b[1] << 16);
  o4.y = (unsigned)b[2] | ((unsigned)b[3] << 16);
  o4.z = (unsigned)b[4] | ((unsigned)b[5] << 16);
  o4.w = (unsigned)b[6] | ((unsigned)b[7] << 16);
  *(uint4*)(row + t * 8) = o4;
}

// ---------------- 128x128 NT bf16 MFMA GEMM, C[m,n] = sum_k A[m,k]*B[n,k] ----------------
// EPI 1: C=bf16( acc * (1/32) )
// EPI 2: C=f32 ( acc + Xadd )  + global absmax -> sc->max_y_bits
template <int EPI>
__global__ __launch_bounds__(256) void gemm_bt(
    const __hip_bfloat16* __restrict__ A, const __hip_bfloat16* __restrict__ B,
    void* __restrict__ C, const float* __restrict__ Xadd,
    Scalars* __restrict__ sc, int Ndim, int Kdim, int nxShift) {
  __shared__ __hip_bfloat16 sA[BM * BK];
  __shared__ __hip_bfloat16 sB[BN * BK];
  __shared__ float wred[4];

  int bx, by;
  tile_swizzle(nxShift, bx, by);
  const int rowBlk = by * BM;
  const int colBlk = bx * BN;

  const int t = threadIdx.x;
  const int w = t >> 6;
  const int l = t & 63;
  const int wm = w >> 1, wn = w & 1;
  const int quad = l >> 4;
  const int m16 = l & 15;
  const int rIn = l >> 3;
  const int dIn = (l & 7) ^ rIn;  // XOR swizzle of 16B sub-chunks within a 128B row

  f32x4 acc[4][4] = {};

  for (int kb = 0; kb < Kdim; kb += BK) {
#pragma unroll
    for (int i = 0; i < 4; ++i) {
      const int c = w + 4 * i;  // 1KB chunk = 8 rows x 128B
      const int r = 8 * c + rIn;
      async16(&sA[c * 512], A + (size_t)(rowBlk + r) * Kdim + kb + dIn * 8);
      async16(&sB[c * 512], B + (size_t)(colBlk + r) * Kdim + kb + dIn * 8);
    }
    __syncthreads();

#pragma unroll
    for (int ks = 0; ks < 2; ++ks) {
      bf16x8 af[4], bfr[4];
#pragma unroll
      for (int i = 0; i < 4; ++i) {
        const int r = wm * 64 + i * 16 + m16;
        const int p = (ks * 4 + quad) ^ (r & 7);
        af[i] = *(const bf16x8*)(&sA[r * 64 + p * 8]);
      }
#pragma unroll
      for (int j = 0; j < 4; ++j) {
        const int r = wn * 64 + j * 16 + m16;
        const int p = (ks * 4 + quad) ^ (r & 7);
        bfr[j] = *(const bf16x8*)(&sB[r * 64 + p * 8]);
      }
#pragma unroll
      for (int i = 0; i < 4; ++i)
#pragma unroll
        for (int j = 0; j < 4; ++j)
          acc[i][j] = __builtin_amdgcn_mfma_f32_16x16x32_bf16(af[i], bfr[j], acc[i][j], 0, 0, 0);
    }
    __syncthreads();
  }

  float amax = 0.0f;
#pragma unroll
  for (int i = 0; i < 4; ++i) {
#pragma unroll
    for (int j = 0; j < 4; ++j) {
      const int col = colBlk + wn * 64 + j * 16 + m16;
#pragma unroll
      for (int rg = 0; rg < 4; ++rg) {
        const int row = rowBlk + wm * 64 + i * 16 + quad * 4 + rg;
        float v = acc[i][j][rg];
        if (EPI == 1) {
          ((__hip_bfloat16*)C)[(size_t)row * Ndim + col] = __float2bfloat16(v * 0.03125f);
        } else {
          v += Xadd[(size_t)row * Ndim + col];
          ((float*)C)[(size_t)row * Ndim + col] = v;
          amax = fmaxf(amax, fabsf(v));
        }
      }
    }
  }

  if (EPI == 2) {
#pragma unroll
    for (int o = 32; o > 0; o >>= 1) amax = fmaxf(amax, __shfl_xor(amax, o));
    if (l == 0) wred[w] = amax;
    __syncthreads();
    if (t == 0)
      atomicMax(&sc->max_y_bits,
                __float_as_uint(fmaxf(fmaxf(wred[0], wred[1]), fmaxf(wred[2], wred[3]))));
  }
}

// ---------------- 128x128 NT i8 MFMA GEMM (exact BitNet matmul) ----------------
// C[m,n] = sum_k A[m,k]*B[n,k], i32 accumulate (bit-exact vs fp32-of-integers).
// EPI 0: bf16( acc * (wsc_k*isc_x) + bias[col] )
// EPI 1: f32 ( acc * (wsc_o*isc_y) + bias[col] )
template <int EPI>
__global__ __launch_bounds__(256) void gemm_i8(
    const char* __restrict__ A, const char* __restrict__ B, void* __restrict__ C,
    const float* __restrict__ bias, Scalars* __restrict__ sc,
    int Ndim, int Kdim, int nxShift) {
  __shared__ char sA[BM * 128];  // BK=128 bytes per row
  __shared__ char sB[BN * 128];

  int bx, by;
  tile_swizzle(nxShift, bx, by);
  const int rowBlk = by * BM;
  const int colBlk = bx * BN;

  const int t = threadIdx.x;
  const int w = t >> 6;
  const int l = t & 63;
  const int wm = w >> 1, wn = w & 1;
  const int quad = l >> 4;
  const int m16 = l & 15;
  const int rIn = l >> 3;
  const int dIn = (l & 7) ^ rIn;

  i32x4 acc[4][4] = {};

  for (int kb = 0; kb < Kdim; kb += 128) {
#pragma unroll
    for (int i = 0; i < 4; ++i) {
      const int c = w + 4 * i;  // 1KB chunk = 8 rows x 128B
      const int r = 8 * c + rIn;
      async16(&sA[c * 1024], A + (size_t)(rowBlk + r) * Kdim + kb + dIn * 16);
      async16(&sB[c * 1024], B + (size_t)(colBlk + r) * Kdim + kb + dIn * 16);
    }
    __syncthreads();

#pragma unroll
    for (int ks = 0; ks < 2; ++ks) {  // two K=64 MFMA steps per 128B row
      i32x4 af[4], bfr[4];
#pragma unroll
      for (int i = 0; i < 4; ++i) {
        const int r = wm * 64 + i * 16 + m16;
        const int p = (ks * 4 + quad) ^ (r & 7);
        af[i] = *(const i32x4*)(&sA[r * 128 + p * 16]);
      }
#pragma unroll
      for (int j = 0; j < 4; ++j) {
        const int r = wn * 64 + j * 16 + m16;
        const int p = (ks * 4 + quad) ^ (r & 7);
        bfr[j] = *(const i32x4*)(&sB[r * 128 + p * 16]);
      }
#pragma unroll
      for (int i = 0; i < 4; ++i)
#pragma unroll
        for (int j = 0; j < 4; ++j)
          acc[i][j] = __builtin_amdgcn_mfma_i32_16x16x64_i8(af[i], bfr[j], acc[i][j], 0, 0, 0);
    }
    __syncthreads();
  }

  float s;
  if (EPI == 0) {
    s = (float)(sc->sum_wk * (1.0 / 1048576.0)) * (__uint_as_float(sc->max_x_bits) / 127.0f);
  } else {
    s = (float)(sc->sum_wo * (1.0 / 1048576.0)) * (__uint_as_float(sc->max_y_bits) / 127.0f);
  }

#pragma unroll
  for (int i = 0; i < 4; ++i) {
#pragma unroll
    for (int j = 0; j < 4; ++j) {
      const int col = colBlk + wn * 64 + j * 16 + m16;
#pragma unroll
      for (int rg = 0; rg < 4; ++rg) {
        const int row = rowBlk + wm * 64 + i * 16 + quad * 4 + rg;
        const float v = (float)acc[i][j][rg] * s + bias[col];
        if (EPI == 0)
          ((__hip_bfloat16*)C)[(size_t)row * Ndim + col] = __float2bfloat16(v);
        else
          ((float*)C)[(size_t)row * Ndim + col] = v;
      }
    }
  }
}

extern "C" void kernel_launch(void* const* d_in, const int* in_sizes, int n_in,
                              void* d_out, int out_size, void* d_ws, size_t ws_size,
                              hipStream_t stream) {
  (void)in_sizes; (void)n_in; (void)out_size; (void)ws_size;
  const float* x  = (const float*)d_in[0];   // [8,4096,1024]
  const float* mk = (const float*)d_in[1];   // [2048,1024]
  const float* mv = (const float*)d_in[2];   // [2048,1024]
  const float* Wk = (const float*)d_in[3];   // [1024,1024]
  const float* bk = (const float*)d_in[4];   // [1024]
  // d_in[5], d_in[6] = Wv, bv -> dead w.r.t. output; skipped.
  const float* Wo = (const float*)d_in[7];
  const float* bo = (const float*)d_in[8];
  float* out = (float*)d_out;

  const int M = 32768, E = 1024, MEM = 2048;

  char* ws = (char*)d_ws;
  Scalars* sc = (Scalars*)ws;
  const size_t off0 = 256;
  char* qx8 = ws + off0;                                            // 32 MB
  __hip_bfloat16* qk = (__hip_bfloat16*)(ws + off0 + (size_t)M * E); // 64 MB
  float* y = (float*)(ws + off0);                                   // reuses qx8+qk region (128 MB)
  const size_t off1 = off0 + (size_t)M * E * 4;
  __hip_bfloat16* sims = (__hip_bfloat16*)(ws + off1);              // 128 MB
  char* qy8 = (char*)sims;                                          // reuses sims (32 MB)
  const size_t off2 = off1 + (size_t)M * MEM * 2;
  char* qWk8 = ws + off2;                                           // 1 MB
  char* qWo8 = qWk8 + (size_t)E * E;                                // 1 MB
  __hip_bfloat16* mkb = (__hip_bfloat16*)(qWo8 + (size_t)E * E);    // 4 MB
  __hip_bfloat16* mvT = mkb + (size_t)MEM * E;                      // 4 MB

  hipMemsetAsync(ws, 0, 256, stream);

  abssum_kernel<<<dim3(256), dim3(256), 0, stream>>>(Wk, (size_t)E * E, &sc->sum_wk);
  abssum_kernel<<<dim3(256), dim3(256), 0, stream>>>(Wo, (size_t)E * E, &sc->sum_wo);
  absmax_kernel<<<dim3(2048), dim3(256), 0, stream>>>(x, (size_t)M * E, &sc->max_x_bits);

  quant_act_i8_kernel<<<dim3(2048), dim3(256), 0, stream>>>(x, qx8, &sc->max_x_bits, (size_t)M * E);
  quant_w_i8_kernel<<<dim3(256), dim3(256), 0, stream>>>(Wk, qWk8, &sc->sum_wk, (size_t)E * E);
  quant_w_i8_kernel<<<dim3(256), dim3(256), 0, stream>>>(Wo, qWo8, &sc->sum_wo, (size_t)E * E);
  cast_bf16_kernel<<<dim3(256), dim3(256), 0, stream>>>(mk, mkb, (size_t)MEM * E);
  transpose_mv_kernel<<<dim3(E / 32, MEM / 32), dim3(32, 32), 0, stream>>>(mv, mvT);

  // qk = bf16((qx @ qWk^T) * s_k + bk)      [i8 MFMA, exact]
  gemm_i8<0><<<dim3((E / BN) * (M / BM)), dim3(256), 0, stream>>>(qx8, qWk8, qk, bk, sc, E, E, 3);
  // sims = bf16((qk @ mk^T) / 32)
  gemm_bt<1><<<dim3((MEM / BN) * (M / BM)), dim3(256), 0, stream>>>(qk, mkb, sims, nullptr, sc, MEM, E, 4);
  // softmax rows (in place)
  softmax_kernel<<<dim3(M), dim3(256), 0, stream>>>(sims);
  // y = probs @ mv + x   (+ global max|y|)
  gemm_bt<2><<<dim3((E / BN) * (M / BM)), dim3(256), 0, stream>>>(sims, mvT, y, x, sc, E, MEM, 3);
  // qy = quant(y)
  quant_act_i8_kernel<<<dim3(2048), dim3(256), 0, stream>>>(y, qy8, &sc->max_y_bits, (size_t)M * E);
  // out = (qy @ qWo^T) * s_o + bo           [i8 MFMA, exact]
  gemm_i8<1><<<dim3((E / BN) * (M / BM)), dim3(256), 0, stream>>>(qy8, qWo8, out, bo, sc, E, E, 3);
}